// Round 1
// 1353.630 us; speedup vs baseline: 1.4249x; 1.4249x over previous
//
#include <hip/hip_runtime.h>

#define BS 256
// ---------- multi-kernel path: ws float layout ----------
// stats: 45 slots x 1024 floats (16 reps x (32 sums + 32 sumsq))
#define STATS_F   0
#define W2T_F     46080            // 65536 floats: transposed end_conv2_w [k][o]
#define XBUF_F    131072           // 2^21 floats: x state [c][p]
#define RBUF_F    2228224          // 2^21 floats: r state [c][p]
#define WS_NEED_BYTES (4325376ull * 4ull)

__device__ __forceinline__ void mish2(float v, float& mp, float& mn) {
  // mish(v) = v*(u^2+2u)/(u^2+2u+2), u=e^v ; mish(-v) = -v*(2u+1)/(2u^2+2u+1)
  float vc = fminf(fmaxf(v, -30.f), 30.f);
  float u  = __expf(vc);
  float n1 = u * (u + 2.f);
  mp = v * n1 * __builtin_amdgcn_rcpf(n1 + 2.f);
  float n2 = fmaf(2.f, u, 1.f);
  float d2 = fmaf(2.f * u, u, n2);
  mn = -v * n2 * __builtin_amdgcn_rcpf(d2);
}

// Per-block reduce of 32 per-thread values -> 32 sums + 32 sumsq, atomically
// added to slot[(blockIdx&15)*64 + q] (16 replicas -> only 16 RMW per address).
__device__ __forceinline__ void block_reduce_stats(const float (&vals)[32],
    float* s_red, float* s_p2, float* slot, int t) {
  #pragma unroll
  for (int cc = 0; cc < 8; ++cc) {
    float4 v = make_float4(vals[cc*4+0], vals[cc*4+1], vals[cc*4+2], vals[cc*4+3]);
    *(float4*)(&s_red[t*32 + ((cc ^ (t & 7)) << 2)]) = v;  // xor-swizzle: conflict-free
  }
  __syncthreads();
  {
    int q = t & 63, grp = t >> 6, c = q & 31;
    bool issq = (q >= 32);
    float acc = 0.f;
    #pragma clang loop unroll_count(8)
    for (int rr = 0; rr < 64; ++rr) {
      int row = grp * 64 + rr;
      float v = s_red[row*32 + ((((c >> 2) ^ (row & 7)) << 2) | (c & 3))];
      acc = fmaf(v, issq ? v : 1.f, acc);
    }
    s_p2[t] = acc;
  }
  __syncthreads();
  if (t < 64) {
    float tot = s_p2[t] + s_p2[t+64] + s_p2[t+128] + s_p2[t+192];
    unsafeAtomicAdd(&slot[(blockIdx.x & 15) * 64 + t], tot);
  }
  __syncthreads();   // allow LDS reuse by caller
}

// Finalize BN over a 32-channel slot (written by previous kernel's atomics).
__device__ __forceinline__ void bn32_from_slot(const float* slot, const float* g,
    const float* b, float* sA, float* sB, float* s_tmp, int t) {
  if (t < 64) {
    float s = 0.f;
    #pragma unroll
    for (int rep = 0; rep < 16; ++rep) s += slot[rep*64 + t];
    s_tmp[t] = s;
  }
  __syncthreads();
  if (t < 32) {
    float mean = s_tmp[t] * (1.f/65536.f);
    float var  = fmaf(-mean, mean, s_tmp[t+32] * (1.f/65536.f));
    float sc   = g[t] * rsqrtf(var + 1e-5f);
    sA[t] = sc;
    sB[t] = fmaf(-mean, sc, b[t]);
  }
  __syncthreads();
}

// Gate->mish->res for layer i from state x; r out.  (global-weight version,
// used by the fallback persistent kernel only)
__device__ __forceinline__ void layer_convs(const float (&x)[32], float (&r)[32],
    const float* gw, const float* gb, const float* rw, const float* rb, int i) {
  float g[16];
  #pragma unroll
  for (int j = 0; j < 16; ++j) g[j] = gb[i*16 + j];
  #pragma unroll
  for (int j = 0; j < 16; ++j)
    #pragma unroll
    for (int k = 0; k < 32; ++k)
      g[j] = fmaf(gw[i*512 + j*32 + k], x[k], g[j]);
  float cm[32];
  #pragma unroll
  for (int j = 0; j < 16; ++j) mish2(g[j], cm[j], cm[j+16]);
  #pragma unroll
  for (int j = 0; j < 32; ++j) r[j] = rb[i*32 + j];
  #pragma unroll
  for (int j = 0; j < 32; ++j)
    #pragma unroll
    for (int k = 0; k < 32; ++k)
      r[j] = fmaf(rw[i*1024 + j*32 + k], cm[k], r[j]);
}

// LDS-weight version: wg = 512 floats (gate), wrs = 1024 floats (res), both in
// LDS; broadcast ds_read_b128 (same-address across lanes = conflict-free).
// Same per-row FMA order as layer_convs -> bitwise-identical results.
__device__ __forceinline__ void layer_convs_lds(const float (&x)[32], float (&r)[32],
    const float* wg, const float* gbv, const float* wrs, const float* rbv) {
  float g[16];
  #pragma unroll
  for (int j = 0; j < 16; ++j) g[j] = gbv[j];
  #pragma unroll
  for (int j = 0; j < 16; ++j) {
    const float4* w = (const float4*)&wg[j*32];
    #pragma unroll
    for (int k4 = 0; k4 < 8; ++k4) {
      float4 a = w[k4];
      g[j] = fmaf(a.x, x[k4*4+0], g[j]);
      g[j] = fmaf(a.y, x[k4*4+1], g[j]);
      g[j] = fmaf(a.z, x[k4*4+2], g[j]);
      g[j] = fmaf(a.w, x[k4*4+3], g[j]);
    }
  }
  float cm[32];
  #pragma unroll
  for (int j = 0; j < 16; ++j) mish2(g[j], cm[j], cm[j+16]);
  #pragma unroll
  for (int j = 0; j < 32; ++j) r[j] = rbv[j];
  #pragma unroll
  for (int j = 0; j < 32; ++j) {
    const float4* w = (const float4*)&wrs[j*32];
    #pragma unroll
    for (int k4 = 0; k4 < 8; ++k4) {
      float4 a = w[k4];
      r[j] = fmaf(a.x, cm[k4*4+0], r[j]);
      r[j] = fmaf(a.y, cm[k4*4+1], r[j]);
      r[j] = fmaf(a.z, cm[k4*4+2], r[j]);
      r[j] = fmaf(a.w, cm[k4*4+3], r[j]);
    }
  }
}

// ---- K_start: w2 transpose + start conv + layer 0 + stats slot 0
__global__ void __launch_bounds__(BS) k_start(const float* __restrict__ xin,
    const float* __restrict__ sw, const float* __restrict__ sb,
    const float* __restrict__ gw, const float* __restrict__ gb,
    const float* __restrict__ rw, const float* __restrict__ rb,
    const float* __restrict__ c2w, float* __restrict__ ws) {
  __shared__ float s_red[BS*32];     // 32 KB; doubles as sw stage (disjoint lifetime)
  __shared__ float s_p2[BS];
  __shared__ float s_w[1536];        // layer-0 gate(512)+res(1024) weights
  int t = threadIdx.x, p = blockIdx.x * BS + t;
  float* w2t = ws + W2T_F; float* xb = ws + XBUF_F; float* rbf = ws + RBUF_F;
  float* s_sw = s_red;               // alias: sw tile lives until conv done
  // stage sw (8192 floats) + layer-0 weights into LDS (parallel vector loads)
  {
    const float4* s4 = (const float4*)sw;
    float4* d4 = (float4*)s_sw;
    #pragma unroll
    for (int q = 0; q < 8; ++q) d4[q*BS + t] = s4[q*BS + t];
    if (t < 128) ((float4*)s_w)[t] = ((const float4*)gw)[t];
    ((float4*)(s_w + 512))[t] = ((const float4*)rw)[t];
  }
  { int o = p & 255, kk = p >> 8; w2t[kk*256 + o] = c2w[o*256 + kk]; }
  __syncthreads();
  int bb = p >> 13, ll = p & 8191;
  int pbase = bb * 2097152 + ll;
  float x[32];
  #pragma unroll
  for (int j = 0; j < 32; ++j) x[j] = sb[j];
  #pragma clang loop unroll(disable)
  for (int c8 = 0; c8 < 32; ++c8) {
    float xv[8];
    #pragma unroll
    for (int cc = 0; cc < 8; ++cc) xv[cc] = xin[pbase + (c8*8+cc)*8192];
    #pragma unroll
    for (int j = 0; j < 32; ++j)
      #pragma unroll
      for (int cc = 0; cc < 8; ++cc)
        x[j] = fmaf(s_sw[j*256 + c8*8 + cc], xv[cc], x[j]);
  }
  float r[32];
  layer_convs_lds(x, r, s_w, gb, s_w + 512, rb);
  #pragma unroll
  for (int c = 0; c < 32; ++c) { xb[c*65536 + p] = x[c]; rbf[c*65536 + p] = r[c]; }
  __syncthreads();   // s_red (aliased as s_sw) is about to be reused by stats
  block_reduce_stats(r, s_red, s_p2, ws + STATS_F, t);
}

// ---- K_layer(i): apply bn_{i-1} to r_{i-1}, update x, compute r_i + stats slot i
__global__ void __launch_bounds__(BS) k_layer(const float* __restrict__ gw,
    const float* __restrict__ gb, const float* __restrict__ rw,
    const float* __restrict__ rb, const float* __restrict__ bng,
    const float* __restrict__ bnb, float* __restrict__ ws, int i) {
  __shared__ float s_red[BS*32];
  __shared__ float s_p2[BS];
  __shared__ float s_A[32], s_B[32], s_tmp[64];
  __shared__ float s_w[1536];        // this layer's gate+res weights
  int t = threadIdx.x, p = blockIdx.x * BS + t;
  float* stats = ws + STATS_F; float* xb = ws + XBUF_F; float* rbf = ws + RBUF_F;
  // stage weights: one parallel coalesced round (kills serialized cold misses);
  // bn32_from_slot's internal barriers provide LDS visibility before use.
  if (t < 128) ((float4*)s_w)[t] = ((const float4*)(gw + i*512))[t];
  ((float4*)(s_w + 512))[t] = ((const float4*)(rw + i*1024))[t];
  bn32_from_slot(stats + (i-1)*1024, bng + (i-1)*32, bnb + (i-1)*32, s_A, s_B, s_tmp, t);
  float x[32], r[32];
  #pragma unroll
  for (int c = 0; c < 32; ++c) { x[c] = xb[c*65536 + p]; r[c] = rbf[c*65536 + p]; }
  #pragma unroll
  for (int c = 0; c < 32; ++c) x[c] += fmaf(r[c], s_A[c], s_B[c]);
  float rn[32];
  layer_convs_lds(x, rn, s_w, gb + i*16, s_w + 512, rb + i*32);
  #pragma unroll
  for (int c = 0; c < 32; ++c) { xb[c*65536 + p] = x[c]; rbf[c*65536 + p] = rn[c]; }
  block_reduce_stats(rn, s_red, s_p2, stats + i*1024, t);
}

// ---- K_end1: apply bn_39, write final residual x, stats of x -> slot 40
__global__ void __launch_bounds__(BS) k_end1(const float* __restrict__ bng,
    const float* __restrict__ bnb, float* __restrict__ ws) {
  __shared__ float s_red[BS*32];
  __shared__ float s_p2[BS];
  __shared__ float s_A[32], s_B[32], s_tmp[64];
  int t = threadIdx.x, p = blockIdx.x * BS + t;
  float* stats = ws + STATS_F; float* xb = ws + XBUF_F; float* rbf = ws + RBUF_F;
  bn32_from_slot(stats + 39*1024, bng + 39*32, bnb + 39*32, s_A, s_B, s_tmp, t);
  float x[32];
  #pragma unroll
  for (int c = 0; c < 32; ++c) {
    float r = rbf[c*65536 + p];
    x[c] = xb[c*65536 + p] + fmaf(r, s_A[c], s_B[c]);
    xb[c*65536 + p] = x[c];
  }
  block_reduce_stats(x, s_red, s_p2, stats + 40*1024, t);
}

// ---- K_end2: bn1 -> concat_mish -> conv1 (recompute later); stats slots 41..44
__global__ void __launch_bounds__(BS) k_end2(const float* __restrict__ e1g,
    const float* __restrict__ e1b, const float* __restrict__ c1w,
    const float* __restrict__ c1b, float* __restrict__ ws) {
  __shared__ float s_red[BS*32];
  __shared__ float s_p2[BS];
  __shared__ float s_A[32], s_B[32], s_tmp[64];
  __shared__ float s_c1wp[2048];     // per-pp c1w chunk (8 KB)
  __shared__ float s_c1b[128];
  int t = threadIdx.x, p = blockIdx.x * BS + t;
  float* stats = ws + STATS_F; float* xb = ws + XBUF_F;
  if (t < 32) ((float4*)s_c1b)[t] = ((const float4*)c1b)[t];
  bn32_from_slot(stats + 40*1024, e1g, e1b, s_A, s_B, s_tmp, t);
  float mp[32], mn[32];
  #pragma unroll
  for (int c = 0; c < 32; ++c) {
    float xh = fmaf(xb[c*65536 + p], s_A[c], s_B[c]);
    mish2(xh, mp[c], mn[c]);
  }
  #pragma clang loop unroll(disable)
  for (int pp = 0; pp < 4; ++pp) {
    // stage this chunk's 32 rows (2048 floats); prev brs's trailing barrier
    // guarantees all threads finished reading the previous chunk.
    { const float4* s = (const float4*)(c1w + pp*2048);
      float4* d = (float4*)s_c1wp;
      d[t] = s[t]; d[256 + t] = s[256 + t]; }
    __syncthreads();
    float zc[32];
    #pragma unroll
    for (int j = 0; j < 32; ++j) zc[j] = s_c1b[pp*32 + j];
    #pragma unroll
    for (int j = 0; j < 32; ++j) {
      const float4* cw = (const float4*)&s_c1wp[j*64];
      #pragma unroll
      for (int k4 = 0; k4 < 8; ++k4) {
        float4 a = cw[k4], b = cw[8+k4];
        zc[j] = fmaf(a.x, mp[k4*4+0], zc[j]);
        zc[j] = fmaf(a.y, mp[k4*4+1], zc[j]);
        zc[j] = fmaf(a.z, mp[k4*4+2], zc[j]);
        zc[j] = fmaf(a.w, mp[k4*4+3], zc[j]);
        zc[j] = fmaf(b.x, mn[k4*4+0], zc[j]);
        zc[j] = fmaf(b.y, mn[k4*4+1], zc[j]);
        zc[j] = fmaf(b.z, mn[k4*4+2], zc[j]);
        zc[j] = fmaf(b.w, mn[k4*4+3], zc[j]);
      }
    }
    block_reduce_stats(zc, s_red, s_p2, stats + (41+pp)*1024, t);
  }
}

// ---- K_end3 (grid 256 x 4): recompute z, bn2 -> concat_mish -> conv2 chunk -> out
// All weights via LDS broadcast; w2t software-pipelined per kc phase; z fused
// into the j loop (scalar -> no scratch).
__global__ void __launch_bounds__(BS) k_end3(const float* __restrict__ e1g,
    const float* __restrict__ e1b, const float* __restrict__ c1w,
    const float* __restrict__ c1b, const float* __restrict__ e2g,
    const float* __restrict__ e2b, const float* __restrict__ c2b,
    float* __restrict__ out, float* __restrict__ ws) {
  __shared__ float s_A[32], s_B[32], s_tmp[64];
  __shared__ float s_A2[128], s_B2[128];
  __shared__ float s_c1w[8192];      // 32 KB: full conv1 weights
  __shared__ float s_c1b[128];
  __shared__ float s_c2b[64];
  __shared__ float4 wbuf[64][16];    // 16 KB: rows j (w0) / 32+j (w1) of current kc
  int t = threadIdx.x, p = blockIdx.x * BS + t;
  float* stats = ws + STATS_F; float* xb = ws + XBUF_F; float* w2t = ws + W2T_F;
  const int ocb = blockIdx.y * 64;
  const int wr = t >> 2, wc = t & 3;  // staging row / col-quarter
  // stage c1w (8 float4/thread), c1b, c2b chunk, and wbuf phase 0
  { float4* d = (float4*)s_c1w; const float4* s = (const float4*)c1w;
    #pragma unroll
    for (int q = 0; q < 8; ++q) d[q*BS + t] = s[q*BS + t]; }
  if (t < 32) ((float4*)s_c1b)[t] = ((const float4*)c1b)[t];
  else if (t < 48) ((float4*)s_c2b)[t-32] = ((const float4*)(c2b + ocb))[t-32];
  { int kr = (wr < 32) ? wr : (wr + 96);     // k, or k+128 for the -x half
    const float4* s = (const float4*)(w2t + kr*256 + ocb) + wc*4;
    float4* d = &wbuf[wr][wc*4];
    d[0] = s[0]; d[1] = s[1]; d[2] = s[2]; d[3] = s[3]; }
  bn32_from_slot(stats + 40*1024, e1g, e1b, s_A, s_B, s_tmp, t);
  if (t < 128) {
    int pp = t >> 5, c = t & 31;
    const float* sl = stats + (41+pp)*1024;
    float S = 0.f, Q = 0.f;
    #pragma unroll
    for (int rep = 0; rep < 16; ++rep) { S += sl[rep*64 + c]; Q += sl[rep*64 + 32 + c]; }
    float mean = S * (1.f/65536.f);
    float var  = fmaf(-mean, mean, Q * (1.f/65536.f));
    float sc   = e2g[t] * rsqrtf(var + 1e-5f);
    s_A2[t] = sc;
    s_B2[t] = fmaf(-mean, sc, e2b[t]);
  }
  __syncthreads();
  float mp[32], mn[32];
  #pragma unroll
  for (int c = 0; c < 32; ++c) {
    float xh = fmaf(xb[c*65536 + p], s_A[c], s_B[c]);
    mish2(xh, mp[c], mn[c]);
  }
  float acc[64];
  #pragma unroll
  for (int o = 0; o < 64; ++o) acc[o] = s_c2b[o];
  #pragma clang loop unroll(disable)
  for (int kc = 0; kc < 4; ++kc) {
    // prefetch next phase's w2t rows into registers (in flight during compute)
    float4 pa, pb, pc, pd;
    if (kc < 3) {
      int kr = (wr < 32) ? ((kc+1)*32 + wr) : ((kc+1)*32 + wr + 96);
      const float4* s = (const float4*)(w2t + kr*256 + ocb) + wc*4;
      pa = s[0]; pb = s[1]; pc = s[2]; pd = s[3];
    }
    #pragma clang loop unroll_count(2)
    for (int j = 0; j < 32; ++j) {
      const int k = kc*32 + j;
      float z = s_c1b[k];
      const float4* cw = (const float4*)&s_c1w[k*64];
      #pragma unroll
      for (int k4 = 0; k4 < 8; ++k4) {
        float4 a = cw[k4], b = cw[8+k4];
        z = fmaf(a.x, mp[k4*4+0], z);
        z = fmaf(a.y, mp[k4*4+1], z);
        z = fmaf(a.z, mp[k4*4+2], z);
        z = fmaf(a.w, mp[k4*4+3], z);
        z = fmaf(b.x, mn[k4*4+0], z);
        z = fmaf(b.y, mn[k4*4+1], z);
        z = fmaf(b.z, mn[k4*4+2], z);
        z = fmaf(b.w, mn[k4*4+3], z);
      }
      float zh = fmaf(z, s_A2[k], s_B2[k]);
      float mpv, mnv; mish2(zh, mpv, mnv);
      const float4* w0 = wbuf[j];
      const float4* w1 = wbuf[32 + j];
      #pragma unroll
      for (int o4 = 0; o4 < 16; ++o4) {
        float4 a = w0[o4], b = w1[o4];
        acc[o4*4+0] = fmaf(a.x, mpv, fmaf(b.x, mnv, acc[o4*4+0]));
        acc[o4*4+1] = fmaf(a.y, mpv, fmaf(b.y, mnv, acc[o4*4+1]));
        acc[o4*4+2] = fmaf(a.z, mpv, fmaf(b.z, mnv, acc[o4*4+2]));
        acc[o4*4+3] = fmaf(a.w, mpv, fmaf(b.w, mnv, acc[o4*4+3]));
      }
    }
    if (kc < 3) {
      __syncthreads();               // everyone done reading wbuf for phase kc
      float4* d = &wbuf[wr][wc*4];
      d[0] = pa; d[1] = pb; d[2] = pc; d[3] = pd;
      __syncthreads();               // phase kc+1 data visible
    }
  }
  int bb = p >> 13, ll = p & 8191;
  int obase = bb * 2097152 + ocb * 8192 + ll;
  #pragma unroll
  for (int o = 0; o < 64; ++o) out[obase + o*8192] = acc[o];
}

// =================== fallback: R3 persistent kernel (ws too small) ===================
#define NBLK 256
#define CNTS_U  4096
#define W2T_FB  4608
#define STATS_OUT_OFF (8u*1024u*1024u)
#define SLOT_STRIDE 16384

__device__ __forceinline__ float coherent_ld(const float* p) {
  return __hip_atomic_load(p, __ATOMIC_RELAXED, __HIP_MEMORY_SCOPE_AGENT);
}
__device__ __forceinline__ void coherent_st(float* p, float v) {
  __hip_atomic_store(p, v, __ATOMIC_RELAXED, __HIP_MEMORY_SCOPE_AGENT);
}
__device__ __forceinline__ void grid_sync_fb(float* ws, unsigned gen, bool flush) {
  __syncthreads();
  unsigned* flags = (unsigned*)ws;
  unsigned* cnts  = (unsigned*)ws + CNTS_U;
  if (blockIdx.x == 0) {
    if (threadIdx.x == 0) {
      if (flush) __threadfence();
      __hip_atomic_fetch_add(&cnts[0], 1u, __ATOMIC_RELAXED, __HIP_MEMORY_SCOPE_AGENT);
      unsigned sum;
      do {
        __builtin_amdgcn_s_sleep(2);
        sum = 0;
        #pragma unroll
        for (int x = 0; x < 32; ++x)
          sum += __hip_atomic_load(&cnts[x*16], __ATOMIC_RELAXED, __HIP_MEMORY_SCOPE_AGENT);
      } while (sum < gen * NBLK);
    }
    __syncthreads();
    __hip_atomic_store(&flags[threadIdx.x * 16], gen,
                       __ATOMIC_RELAXED, __HIP_MEMORY_SCOPE_AGENT);
  } else {
    if (threadIdx.x == 0) {
      if (flush) __threadfence();
      __hip_atomic_fetch_add(&cnts[(blockIdx.x & 31) * 16], 1u,
                             __ATOMIC_RELAXED, __HIP_MEMORY_SCOPE_AGENT);
      while (__hip_atomic_load(&flags[blockIdx.x * 16],
                               __ATOMIC_RELAXED, __HIP_MEMORY_SCOPE_AGENT) < gen)
        __builtin_amdgcn_s_sleep(2);
    }
    __syncthreads();
  }
}
__device__ __forceinline__ void brs_fb(const float (&vals)[32],
    float* s_red, float* s_p2, float* slot, int t) {
  #pragma unroll
  for (int cc = 0; cc < 8; ++cc) {
    float4 v = make_float4(vals[cc*4+0], vals[cc*4+1], vals[cc*4+2], vals[cc*4+3]);
    *(float4*)(&s_red[t*32 + ((cc ^ (t & 7)) << 2)]) = v;
  }
  __syncthreads();
  {
    int q = t & 63, grp = t >> 6, c = q & 31;
    bool issq = (q >= 32);
    float acc = 0.f;
    #pragma clang loop unroll_count(8)
    for (int rr = 0; rr < 64; ++rr) {
      int row = grp * 64 + rr;
      float v = s_red[row*32 + ((((c >> 2) ^ (row & 7)) << 2) | (c & 3))];
      acc = fmaf(v, issq ? v : 1.f, acc);
    }
    s_p2[t] = acc;
  }
  __syncthreads();
  if (t < 64) {
    float tot = s_p2[t] + s_p2[t+64] + s_p2[t+128] + s_p2[t+192];
    coherent_st(&slot[blockIdx.x * 64 + t], tot);
  }
}

extern "C" __global__ void __launch_bounds__(BS, 1)
qnet_fb(const float* __restrict__ xin,
        const float* __restrict__ sw, const float* __restrict__ sb,
        const float* __restrict__ gw, const float* __restrict__ gb,
        const float* __restrict__ rw, const float* __restrict__ rb,
        const float* __restrict__ bng, const float* __restrict__ bnb,
        const float* __restrict__ e1g, const float* __restrict__ e1b,
        const float* __restrict__ c1w, const float* __restrict__ c1b,
        const float* __restrict__ e2g, const float* __restrict__ e2b,
        const float* __restrict__ c2w, const float* __restrict__ c2b,
        float* __restrict__ out, float* __restrict__ ws)
{
  __shared__ float s_red[BS*32];
  __shared__ float s_p2[BS];
  __shared__ float s_tot[64];
  __shared__ float s_bcA[128];
  __shared__ float s_bcB[128];
  const int t = threadIdx.x;
  const int p = blockIdx.x * BS + t;
  float* w2t = ws + W2T_FB;
  float* zg  = out;
  float* sg  = out + STATS_OUT_OFF;
  unsigned gen = 0;
  const int bb = p >> 13, ll = p & 8191;
  const int pbase = bb * 2097152 + ll;
  { int o = p & 255, kk = p >> 8; coherent_st(&w2t[kk*256 + o], c2w[o*256 + kk]); }
  float x[32];
  #pragma unroll
  for (int j = 0; j < 32; ++j) x[j] = sb[j];
  #pragma clang loop unroll(disable)
  for (int c8 = 0; c8 < 32; ++c8) {
    float xv[8];
    #pragma unroll
    for (int cc = 0; cc < 8; ++cc) xv[cc] = xin[pbase + (c8*8+cc)*8192];
    #pragma unroll
    for (int j = 0; j < 32; ++j)
      #pragma unroll
      for (int cc = 0; cc < 8; ++cc)
        x[j] = fmaf(sw[j*256 + c8*8 + cc], xv[cc], x[j]);
  }
  #pragma clang loop unroll(disable)
  for (int i = 0; i < 40; ++i) {
    float r[32];
    layer_convs(x, r, gw, gb, rw, rb, i);
    brs_fb(r, s_red, s_p2, sg + (size_t)i * SLOT_STRIDE, t);
    ++gen; grid_sync_fb(ws, gen, false);
    {
      int q = t & 63, w = t >> 6;
      const float* col = sg + (size_t)i * SLOT_STRIDE + q;
      float acc2 = 0.f;
      #pragma clang loop unroll_count(16)
      for (int j = 0; j < 64; ++j) acc2 += coherent_ld(&col[(w*64+j)*64]);
      s_p2[t] = acc2;
    }
    __syncthreads();
    if (t < 64) s_tot[t] = s_p2[t] + s_p2[t+64] + s_p2[t+128] + s_p2[t+192];
    __syncthreads();
    if (t < 32) {
      float mean = s_tot[t] * (1.f/65536.f);
      float var  = fmaf(-mean, mean, s_tot[t+32] * (1.f/65536.f));
      float sc   = bng[i*32+t] * rsqrtf(var + 1e-5f);
      s_bcA[t] = sc;
      s_bcB[t] = fmaf(-mean, sc, bnb[i*32+t]);
    }
    __syncthreads();
    #pragma unroll
    for (int c = 0; c < 32; ++c) x[c] += fmaf(r[c], s_bcA[c], s_bcB[c]);
  }
  brs_fb(x, s_red, s_p2, sg + 40 * SLOT_STRIDE, t);
  ++gen; grid_sync_fb(ws, gen, false);
  {
    int q = t & 63, w = t >> 6;
    const float* col = sg + (size_t)40 * SLOT_STRIDE + q;
    float acc2 = 0.f;
    #pragma clang loop unroll_count(16)
    for (int j = 0; j < 64; ++j) acc2 += coherent_ld(&col[(w*64+j)*64]);
    s_p2[t] = acc2;
  }
  __syncthreads();
  if (t < 64) s_tot[t] = s_p2[t] + s_p2[t+64] + s_p2[t+128] + s_p2[t+192];
  __syncthreads();
  if (t < 32) {
    float mean = s_tot[t] * (1.f/65536.f);
    float var  = fmaf(-mean, mean, s_tot[t+32] * (1.f/65536.f));
    float sc   = e1g[t] * rsqrtf(var + 1e-5f);
    s_bcA[t] = sc;
    s_bcB[t] = fmaf(-mean, sc, e1b[t]);
  }
  __syncthreads();
  float mp[32], mn[32];
  #pragma unroll
  for (int c = 0; c < 32; ++c) {
    float xh = fmaf(x[c], s_bcA[c], s_bcB[c]);
    mish2(xh, mp[c], mn[c]);
  }
  #pragma clang loop unroll(disable)
  for (int pp = 0; pp < 4; ++pp) {
    float zc[32];
    #pragma unroll
    for (int j = 0; j < 32; ++j) zc[j] = c1b[pp*32 + j];
    #pragma unroll
    for (int j = 0; j < 32; ++j)
      #pragma unroll
      for (int k = 0; k < 32; ++k) {
        zc[j] = fmaf(c1w[(pp*32+j)*64 + k],      mp[k], zc[j]);
        zc[j] = fmaf(c1w[(pp*32+j)*64 + 32 + k], mn[k], zc[j]);
      }
    #pragma unroll
    for (int j = 0; j < 32; ++j) zg[(pp*32+j)*65536 + p] = zc[j];
    brs_fb(zc, s_red, s_p2, sg + (size_t)(41+pp) * SLOT_STRIDE, t);
    __syncthreads();
  }
  ++gen; grid_sync_fb(ws, gen, false);
  {
    int slot = 41 + (t >> 6), q = t & 63;
    const float* col = sg + (size_t)slot * SLOT_STRIDE + q;
    float acc2 = 0.f;
    #pragma clang loop unroll_count(32)
    for (int b2 = 0; b2 < 256; ++b2) acc2 += coherent_ld(&col[b2*64]);
    s_p2[t] = acc2;
  }
  __syncthreads();
  if (t < 128) {
    float S = s_p2[((t>>5)<<6) | (t&31)];
    float Q = s_p2[((t>>5)<<6) | 32 | (t&31)];
    float mean = S * (1.f/65536.f);
    float var  = fmaf(-mean, mean, Q * (1.f/65536.f));
    float sc   = e2g[t] * rsqrtf(var + 1e-5f);
    s_bcA[t] = sc;
    s_bcB[t] = fmaf(-mean, sc, e2b[t]);
  }
  __syncthreads();
  float acc[256];
  #pragma unroll
  for (int o = 0; o < 256; ++o) acc[o] = c2b[o];
  float zv_next = zg[p];
  #pragma clang loop unroll(disable)
  for (int k = 0; k < 128; ++k) {
    float zv = zv_next;
    zv_next = zg[((k+1)&127)*65536 + p];
    float zh = fmaf(zv, s_bcA[k], s_bcB[k]);
    float mpv, mnv; mish2(zh, mpv, mnv);
    const float* w0 = &w2t[k*256];
    const float* w1 = &w2t[(k+128)*256];
    #pragma unroll
    for (int o = 0; o < 256; ++o)
      acc[o] = fmaf(w0[o], mpv, fmaf(w1[o], mnv, acc[o]));
  }
  ++gen; grid_sync_fb(ws, gen, true);
  #pragma unroll
  for (int o = 0; o < 256; ++o)
    out[bb*2097152 + o*8192 + ll] = acc[o];
}

extern "C" void kernel_launch(void* const* d_in, const int* in_sizes, int n_in,
                              void* d_out, int out_size, void* d_ws, size_t ws_size,
                              hipStream_t stream) {
  const float* xin = (const float*)d_in[0];
  const float* sw  = (const float*)d_in[1];
  const float* sb  = (const float*)d_in[2];
  const float* gw  = (const float*)d_in[3];
  const float* gb  = (const float*)d_in[4];
  const float* rw  = (const float*)d_in[5];
  const float* rb  = (const float*)d_in[6];
  const float* bng = (const float*)d_in[7];
  const float* bnb = (const float*)d_in[8];
  const float* e1g = (const float*)d_in[9];
  const float* e1b = (const float*)d_in[10];
  const float* c1w = (const float*)d_in[11];
  const float* c1b = (const float*)d_in[12];
  const float* e2g = (const float*)d_in[13];
  const float* e2b = (const float*)d_in[14];
  const float* c2w = (const float*)d_in[15];
  const float* c2b = (const float*)d_in[16];
  float* out = (float*)d_out;
  float* ws  = (float*)d_ws;

  if (ws_size >= WS_NEED_BYTES) {
    // multi-kernel graph: 43 launches; kernel boundaries provide all sync
    hipMemsetAsync(d_ws, 0, 45 * 1024 * 4, stream);
    k_start<<<256, BS, 0, stream>>>(xin, sw, sb, gw, gb, rw, rb, c2w, ws);
    for (int i = 1; i < 40; ++i)
      k_layer<<<256, BS, 0, stream>>>(gw, gb, rw, rb, bng, bnb, ws, i);
    k_end1<<<256, BS, 0, stream>>>(bng, bnb, ws);
    k_end2<<<256, BS, 0, stream>>>(e1g, e1b, c1w, c1b, ws);
    k_end3<<<dim3(256, 4), BS, 0, stream>>>(e1g, e1b, c1w, c1b, e2g, e2b, c2b, out, ws);
  } else {
    // fallback: R3 persistent cooperative kernel (proven, ~2.5 ms)
    hipMemsetAsync(d_ws, 0, (CNTS_U + 512) * 4, stream);
    void* args[] = { &xin, &sw, &sb, &gw, &gb, &rw, &rb, &bng, &bnb,
                     &e1g, &e1b, &c1w, &c1b, &e2g, &e2b, &c2w, &c2b, &out, &ws };
    hipError_t err = hipLaunchCooperativeKernel((const void*)qnet_fb,
                                                dim3(NBLK), dim3(BS), args, 0, stream);
    if (err != hipSuccess) {
      hipLaunchKernelGGL(qnet_fb, dim3(NBLK), dim3(BS), 0, stream,
                         xin, sw, sb, gw, gb, rw, rb, bng, bnb,
                         e1g, e1b, c1w, c1b, e2g, e2b, c2w, c2b, out, ws);
    }
  }
}